// Round 6
// baseline (347.862 us; speedup 1.0000x reference)
//
#include <hip/hip_runtime.h>
#include <cstdint>
#include <cstddef>

#define B_ 4
#define S_ 2048
#define D_ 512
#define H_ 8
#define DK_ 64
#define DFF_ 2048

using s16x8  = __attribute__((ext_vector_type(8))) short;
using bf16x8 = __attribute__((ext_vector_type(8))) __bf16;
using f32x4  = __attribute__((ext_vector_type(4))) float;

__device__ __forceinline__ short f2bf(float f) {
  unsigned u = __builtin_bit_cast(unsigned, f);
  u += 0x7FFFu + ((u >> 16) & 1u);
  return (short)(u >> 16);
}
__device__ __forceinline__ float bf2f(short s) {
  unsigned u = ((unsigned)(unsigned short)s) << 16;
  return __builtin_bit_cast(float, u);
}

// async global->LDS, 16 B per lane. LDS dest = wave-uniform base + lane*16.
__device__ __forceinline__ void gl2lds16(const void* g, void* l) {
  __builtin_amdgcn_global_load_lds(
      (const __attribute__((address_space(1))) void*)g,
      (__attribute__((address_space(3))) void*)l, 16, 0, 0);
}

// ---------------- fused f32 -> bf16 conversion (all tensors, one launch) ----------------
__global__ __launch_bounds__(256)
void cvt_all(const float* __restrict__ x, const float* __restrict__ Wq,
             const float* __restrict__ Wk, const float* __restrict__ Wv,
             const float* __restrict__ Wp, const float* __restrict__ W1,
             const float* __restrict__ W2,
             short* __restrict__ xb, short* __restrict__ wqkv,
             short* __restrict__ wp, short* __restrict__ w1, short* __restrict__ w2) {
  int blk = blockIdx.x;
  const float* src; short* dst; int off;
  if (blk < 4096)      { src = x;  dst = xb;            off = blk; }
  else if (blk < 4352) { src = Wq; dst = wqkv;          off = blk - 4096; }
  else if (blk < 4608) { src = Wk; dst = wqkv + 262144; off = blk - 4352; }
  else if (blk < 4864) { src = Wv; dst = wqkv + 524288; off = blk - 4608; }
  else if (blk < 5120) { src = Wp; dst = wp;            off = blk - 4864; }
  else if (blk < 6144) { src = W1; dst = w1;            off = blk - 5120; }
  else                 { src = W2; dst = w2;            off = blk - 6144; }
  int i = (off * 256 + threadIdx.x) * 4;
  float4 v = *(const float4*)(src + i);
  *(short4*)(dst + i) = make_short4(f2bf(v.x), f2bf(v.y), f2bf(v.z), f2bf(v.w));
}

// ---------------- mask dtype detect + convert ----------------
__global__ __launch_bounds__(256) void mask_detect(const unsigned* __restrict__ m,
                                                   unsigned* __restrict__ flag) {
  int i = blockIdx.x * 256 + threadIdx.x;  // 0..2047
  unsigned v = m[i];
  if (v) atomicOr(flag, v);
}

__global__ __launch_bounds__(256) void mask_convert(const void* __restrict__ m,
                                                    const unsigned* __restrict__ flag,
                                                    float* __restrict__ mb) {
  int i = blockIdx.x * 256 + threadIdx.x;  // 0..8191
  unsigned f = *flag;
  int v;
  if ((f & ~1u) == 0u)            v = ((const int*)m)[i];
  else if (f == 0x3F800000u)      v = (((const float*)m)[i] != 0.0f);
  else                            v = ((const unsigned char*)m)[i];
  mb[i] = v ? 0.0f : -100.0f;
}

// ---------------- bf16 MFMA GEMM (m97-style, 256t, 128x128): C = A * B^T ----------------
// MODE 0: fused QKV (N=1536): n<512 -> Q^T*0.125 to [B,H,64,S]; n<1024 -> K to [B,H,S,64];
//         else V^T to [B,H,64,S]. Transposed outs use short4 along m.
// MODE 2: write bf16 [m*N+n] = gelu(acc + aux1[n])             (FF1 + bias + GELU)
constexpr int BM = 128, BN = 128, BK = 32;

template <int MODE>
__global__ __launch_bounds__(256)
void gemm_bt(const short* __restrict__ A, const short* __restrict__ B,
             int M, int N, int K,
             const float* __restrict__ aux1,
             void* __restrict__ out0, void* __restrict__ out1, void* __restrict__ out2) {
  __shared__ alignas(16) short As[BM][BK];  // unpadded: global_load_lds order
  __shared__ alignas(16) short Bs[BN][BK];

  const int tid  = threadIdx.x;
  const int lane = tid & 63;
  const int wave = tid >> 6;
  const int quad = lane >> 4;
  const int l16  = lane & 15;
  const int wm   = (wave >> 1) * 64;
  const int wn   = (wave & 1) * 64;
  const int bm   = blockIdx.x * BM;
  const int bn   = blockIdx.y * BN;

  const short* Ag = A + (size_t)(bm + wave * 32 + (lane >> 2)) * K + (lane & 3) * 8;
  const short* Bg = B + (size_t)(bn + wave * 32 + (lane >> 2)) * K + (lane & 3) * 8;
  short* AsW = &As[wave * 32][0];
  short* BsW = &Bs[wave * 32][0];
  const size_t row16 = (size_t)16 * K;

  f32x4 acc[4][4] = {};

  for (int k0 = 0; k0 < K; k0 += BK) {
    gl2lds16(Ag + k0,          AsW);
    gl2lds16(Ag + k0 + row16,  AsW + 16 * BK);
    gl2lds16(Bg + k0,          BsW);
    gl2lds16(Bg + k0 + row16,  BsW + 16 * BK);
    __syncthreads();

    bf16x8 a[4], b[4];
#pragma unroll
    for (int i = 0; i < 4; ++i)
      a[i] = __builtin_bit_cast(bf16x8, *(const s16x8*)&As[wm + i * 16 + l16][quad * 8]);
#pragma unroll
    for (int j = 0; j < 4; ++j)
      b[j] = __builtin_bit_cast(bf16x8, *(const s16x8*)&Bs[wn + j * 16 + l16][quad * 8]);
#pragma unroll
    for (int i = 0; i < 4; ++i)
#pragma unroll
      for (int j = 0; j < 4; ++j)
        acc[i][j] = __builtin_amdgcn_mfma_f32_16x16x32_bf16(a[i], b[j], acc[i][j], 0, 0, 0);
    __syncthreads();
  }

#pragma unroll
  for (int i = 0; i < 4; ++i) {
    const int m0 = bm + wm + i * 16 + quad * 4;
#pragma unroll
    for (int j = 0; j < 4; ++j) {
      const int n = bn + wn + j * 16 + l16;
      if constexpr (MODE == 0) {
        const int bb = m0 >> 11, ss0 = m0 & 2047;
        if (n < 512) {  // Q^T -> [B,H,64,S], scaled 1/8, short4 along m
          short4 pk = make_short4(f2bf(acc[i][j][0] * 0.125f), f2bf(acc[i][j][1] * 0.125f),
                                  f2bf(acc[i][j][2] * 0.125f), f2bf(acc[i][j][3] * 0.125f));
          *(short4*)((short*)out0 +
              ((((size_t)bb * H_ + (n >> 6)) * 64 + (n & 63)) * S_ + ss0)) = pk;
        } else if (n >= 1024) {  // V^T -> [B,H,64,S], short4 along m
          const int nn = n - 1024;
          short4 pk = make_short4(f2bf(acc[i][j][0]), f2bf(acc[i][j][1]),
                                  f2bf(acc[i][j][2]), f2bf(acc[i][j][3]));
          *(short4*)((short*)out2 +
              ((((size_t)bb * H_ + (nn >> 6)) * 64 + (nn & 63)) * S_ + ss0)) = pk;
        } else {  // K -> [B,H,S,64]
          const int nn = n - 512;
          const int hh = nn >> 6, dd = nn & 63;
          const size_t rowb = ((size_t)bb * H_ + hh) * S_ + ss0;
#pragma unroll
          for (int rr = 0; rr < 4; ++rr)
            ((short*)out1)[(rowb + rr) * 64 + dd] = f2bf(acc[i][j][rr]);
        }
      } else {  // MODE 2: gelu(acc + bias) -> bf16
#pragma unroll
        for (int rr = 0; rr < 4; ++rr) {
          float t = acc[i][j][rr] + aux1[n];
          float gl = 0.5f * t * (1.0f + erff(t * 0.70710678118f));
          ((short*)out0)[(size_t)(m0 + rr) * N + n] = f2bf(gl);
        }
      }
    }
  }
}

// ---------------- 2-wave 128x64 GEMM for N=512 shapes ----------------
// MODE 1: f32 out = acc + aux1[m*N+n]            (proj + f32 residual)
// MODE 3: f32 out = acc + aux1[n] + bf2f(auxb)   (FF2 + bias + bf16 residual)
template <int MODE>
__global__ __launch_bounds__(128)
void gemm_bt2(const short* __restrict__ A, const short* __restrict__ B,
              int M, int N, int K,
              const float* __restrict__ aux1, const short* __restrict__ auxb,
              float* __restrict__ out0) {
  __shared__ alignas(16) short As[128][32];
  __shared__ alignas(16) short Bs[64][32];

  const int tid  = threadIdx.x;
  const int lane = tid & 63;
  const int wave = tid >> 6;       // 0..1
  const int quad = lane >> 4;
  const int l16  = lane & 15;
  const int wm   = wave * 64;
  const int bm   = blockIdx.x * 128;
  const int bn   = blockIdx.y * 64;

  const int srow = wave * 16 + (lane >> 2);
  const int scol = (lane & 3) * 8;
  const short* Ag = A + (size_t)(bm + srow) * K + scol;
  const short* Bg = B + (size_t)(bn + srow) * K + scol;
  short* AsW = &As[wave * 16][0];
  short* BsW = &Bs[wave * 16][0];
  const size_t row32 = (size_t)32 * K;

  f32x4 acc[4][4] = {};

  for (int k0 = 0; k0 < K; k0 += 32) {
    gl2lds16(Ag + k0,              AsW);
    gl2lds16(Ag + k0 + row32,      AsW + 32 * 32);
    gl2lds16(Ag + k0 + 2 * row32,  AsW + 64 * 32);
    gl2lds16(Ag + k0 + 3 * row32,  AsW + 96 * 32);
    gl2lds16(Bg + k0,              BsW);
    gl2lds16(Bg + k0 + row32,      BsW + 32 * 32);
    __syncthreads();

    bf16x8 a[4], b[4];
#pragma unroll
    for (int i = 0; i < 4; ++i)
      a[i] = __builtin_bit_cast(bf16x8, *(const s16x8*)&As[wm + i * 16 + l16][quad * 8]);
#pragma unroll
    for (int j = 0; j < 4; ++j)
      b[j] = __builtin_bit_cast(bf16x8, *(const s16x8*)&Bs[j * 16 + l16][quad * 8]);
#pragma unroll
    for (int i = 0; i < 4; ++i)
#pragma unroll
      for (int j = 0; j < 4; ++j)
        acc[i][j] = __builtin_amdgcn_mfma_f32_16x16x32_bf16(a[i], b[j], acc[i][j], 0, 0, 0);
    __syncthreads();
  }

#pragma unroll
  for (int i = 0; i < 4; ++i) {
    const int m0 = bm + wm + i * 16 + quad * 4;
#pragma unroll
    for (int j = 0; j < 4; ++j) {
      const int n = bn + j * 16 + l16;
#pragma unroll
      for (int rr = 0; rr < 4; ++rr) {
        float v = acc[i][j][rr];
        if constexpr (MODE == 1) {
          out0[(size_t)(m0 + rr) * N + n] = v + aux1[(size_t)(m0 + rr) * N + n];
        } else {
          out0[(size_t)(m0 + rr) * N + n] =
              v + aux1[n] + bf2f(auxb[(size_t)(m0 + rr) * N + n]);
        }
      }
    }
  }
}

// ---------------- MFMA flash attention v4 ----------------
// 2-wave blocks, 128 q-rows/block, 64 q-rows/wave in 4 strips of 16.
// LDS-throughput-bound analysis: K/V-frag reads + staging are per-tile costs
// amortized over 4 strips (2x v3); Ps round-trip scales with q (irreducible
// lane-scatter). Register prefetch of next K/V tile. Fixed-max softmax,
// truncated-P consistent with li. Q read from Q^T [B,H,64,S] once per block.
__global__ __launch_bounds__(128, 1)
void flash_attn_mfma(const short* __restrict__ QTg, const short* __restrict__ Kb,
                     const short* __restrict__ Vtg, const float* __restrict__ maskbias,
                     short* __restrict__ ctxb) {
  __shared__ alignas(16) short Ks[64][72];
  __shared__ alignas(16) short Vt[64][72];
  __shared__ alignas(16) short Ps[2][64][72];
  __shared__ alignas(16) float mrow[S_];

  const int b = blockIdx.z, h = blockIdx.y;
  const int tid = threadIdx.x;
  const int w = tid >> 6, lane = tid & 63;
  const int quad = lane >> 4, l16 = lane & 15;
  const size_t base  = ((size_t)(b * H_ + h)) * S_ * DK_;  // K   [B,H,S,64]
  const size_t baseT = ((size_t)(b * H_ + h)) * DK_ * S_;  // Q^T/V^T [B,H,64,S]
  const int q0 = blockIdx.x * 128;

  // mask row for this batch -> LDS (fenced by first in-loop barrier)
  {
    const float4* mp = (const float4*)(maskbias + (size_t)b * S_);
#pragma unroll
    for (int i = 0; i < 4; ++i) ((float4*)mrow)[tid + i * 128] = mp[tid + i * 128];
  }

  // Q fragments from Q^T: 4 strips x 2 k-halves, gathered once per block
  bf16x8 qa[4][2];
#pragma unroll
  for (int st = 0; st < 4; ++st) {
    const int q = q0 + w * 64 + st * 16 + l16;
#pragma unroll
    for (int c = 0; c < 2; ++c) {
      s16x8 t;
#pragma unroll
      for (int j = 0; j < 8; ++j)
        t[j] = QTg[baseT + (size_t)(c * 32 + quad * 8 + j) * S_ + q];
      qa[st][c] = __builtin_bit_cast(bf16x8, t);
    }
  }

  f32x4 Oc[4][4] = {};
  float li[4][4] = {};

  const int r = tid >> 1, c32 = (tid & 1) * 32;  // 2 threads/row, 64 B each
  const short* kp = Kb  + base  + (size_t)r * 64 + c32;   // row = key
  const short* vp = Vtg + baseT + (size_t)r * S_ + c32;   // row = d, col = key

  // preload tile 0
  s16x8 kr[4], vr[4];
#pragma unroll
  for (int u = 0; u < 4; ++u) {
    kr[u] = *(const s16x8*)(kp + u * 8);
    vr[u] = *(const s16x8*)(vp + u * 8);
  }

  for (int t0 = 0; t0 < S_; t0 += 64) {
    __syncthreads();  // prev tile consumers done (also fences mrow on iter 0)
#pragma unroll
    for (int u = 0; u < 4; ++u) {
      *(s16x8*)&Ks[r][c32 + u * 8] = kr[u];
      *(s16x8*)&Vt[r][c32 + u * 8] = vr[u];
    }
    __syncthreads();

    if (t0 + 64 < S_) {  // prefetch next tile during compute
#pragma unroll
      for (int u = 0; u < 4; ++u) {
        kr[u] = *(const s16x8*)(kp + (size_t)(t0 + 64) * 64 + u * 8);
        vr[u] = *(const s16x8*)(vp + (t0 + 64) + u * 8);
      }
    }

    // S = Q K^T : 4 strips share each K fragment
    f32x4 sc[4][4] = {};
#pragma unroll
    for (int c = 0; c < 2; ++c) {
#pragma unroll
      for (int jt = 0; jt < 4; ++jt) {
        bf16x8 kb = __builtin_bit_cast(bf16x8,
            *(const s16x8*)&Ks[jt * 16 + l16][c * 32 + quad * 8]);
#pragma unroll
        for (int st = 0; st < 4; ++st)
          sc[st][jt] = __builtin_amdgcn_mfma_f32_16x16x32_bf16(qa[st][c], kb, sc[st][jt], 0, 0, 0);
      }
    }

    float mb4[4];
#pragma unroll
    for (int jt = 0; jt < 4; ++jt) mb4[jt] = mrow[t0 + jt * 16 + l16];
#pragma unroll
    for (int st = 0; st < 4; ++st) {
#pragma unroll
      for (int jt = 0; jt < 4; ++jt) {
#pragma unroll
        for (int rr = 0; rr < 4; ++rr) {
          float p = __expf(sc[st][jt][rr] + mb4[jt]);
          unsigned u = __builtin_bit_cast(unsigned, p) & 0xFFFF0000u;
          li[st][rr] += __builtin_bit_cast(float, u);
          Ps[w][st * 16 + quad * 4 + rr][jt * 16 + l16] = (short)(u >> 16);
        }
      }
    }

    // O += P V : 4 strips share each V fragment
#pragma unroll
    for (int c = 0; c < 2; ++c) {
      bf16x8 pa[4];
#pragma unroll
      for (int st = 0; st < 4; ++st)
        pa[st] = __builtin_bit_cast(bf16x8,
            *(const s16x8*)&Ps[w][st * 16 + l16][c * 32 + quad * 8]);
#pragma unroll
      for (int dt = 0; dt < 4; ++dt) {
        bf16x8 vb = __builtin_bit_cast(bf16x8,
            *(const s16x8*)&Vt[dt * 16 + l16][c * 32 + quad * 8]);
#pragma unroll
        for (int st = 0; st < 4; ++st)
          Oc[st][dt] = __builtin_amdgcn_mfma_f32_16x16x32_bf16(pa[st], vb, Oc[st][dt], 0, 0, 0);
      }
    }
  }

#pragma unroll
  for (int st = 0; st < 4; ++st) {
#pragma unroll
    for (int rr = 0; rr < 4; ++rr) {
      float l = li[st][rr];
#pragma unroll
      for (int m = 1; m < 16; m <<= 1) l += __shfl_xor(l, m);
      float inv = 1.f / l;
      const size_t row = (size_t)b * S_ + q0 + w * 64 + st * 16 + quad * 4 + rr;
#pragma unroll
      for (int dt = 0; dt < 4; ++dt)
        ctxb[row * (H_ * DK_) + h * 64 + dt * 16 + l16] = f2bf(Oc[st][dt][rr] * inv);
    }
  }
}

// ---------------- LayerNorm: one wave per token (D=512, 8 elems/lane) ----------------
__global__ __launch_bounds__(256)
void ln_kernel(const float* __restrict__ y, const float* __restrict__ g,
               const float* __restrict__ bb, float* __restrict__ out32,
               short* __restrict__ outb) {
  const int wave = threadIdx.x >> 6, lane = threadIdx.x & 63;
  const int token = blockIdx.x * 4 + wave;
  const float* row = y + (size_t)token * D_;
  float4 v0 = *(const float4*)(row + lane * 8);
  float4 v1 = *(const float4*)(row + lane * 8 + 4);
  float sum = v0.x + v0.y + v0.z + v0.w + v1.x + v1.y + v1.z + v1.w;
#pragma unroll
  for (int m = 1; m < 64; m <<= 1) sum += __shfl_xor(sum, m);
  float mu = sum * (1.0f / D_);
  float d0 = v0.x - mu, d1 = v0.y - mu, d2 = v0.z - mu, d3 = v0.w - mu;
  float d4 = v1.x - mu, d5 = v1.y - mu, d6 = v1.z - mu, d7 = v1.w - mu;
  float vs = d0*d0 + d1*d1 + d2*d2 + d3*d3 + d4*d4 + d5*d5 + d6*d6 + d7*d7;
#pragma unroll
  for (int m = 1; m < 64; m <<= 1) vs += __shfl_xor(vs, m);
  float rstd = rsqrtf(vs * (1.0f / D_) + 1e-5f);
  float o[8] = {d0, d1, d2, d3, d4, d5, d6, d7};
  int c = lane * 8;
#pragma unroll
  for (int i = 0; i < 8; ++i) {
    float val = o[i] * rstd * g[c + i] + bb[c + i];
    if (out32) out32[(size_t)token * D_ + c + i] = val;
    if (outb)  outb[(size_t)token * D_ + c + i] = f2bf(val);
  }
}

// ---------------- workspace layout (bytes) ----------------
constexpr size_t OFF_XB   = 0;                       // [8192,512] bf16
constexpr size_t OFF_WQKV = 8388608;                 // [1536,512] bf16 (Wq|Wk|Wv)
constexpr size_t OFF_WP   = 9961472;                 // [512,512] bf16
constexpr size_t OFF_W1   = 10485760;                // [2048,512] bf16
constexpr size_t OFF_W2   = 12582912;                // [512,2048] bf16
constexpr size_t OFF_QT   = 14680064;                // [B,H,64,S] bf16 (transposed!)
constexpr size_t OFF_K    = 23068672;                // [B,H,S,64] bf16
constexpr size_t OFF_VT   = 31457280;                // [B,H,64,S] bf16 (transposed!)
constexpr size_t OFF_CTX  = 39845888;                // [8192,512] bf16
constexpr size_t OFF_Y1   = 48234496;                // [8192,512] f32
constexpr size_t OFF_HB   = 81788928;                // [8192,512] bf16 (LN1 out)
constexpr size_t OFF_FF1  = 14680064;                // [8192,2048] bf16 (reuses QT/K/VT/CTX)
constexpr size_t OFF_Y2   = 48234496;                // [8192,512] f32 (reuses Y1)
constexpr size_t OFF_MB   = 90177536;                // [8192] f32 mask bias
constexpr size_t OFF_FLAG = 90210304;                // 4 bytes
constexpr size_t WS_NEED  = 90210308;

extern "C" void kernel_launch(void* const* d_in, const int* in_sizes, int n_in,
                              void* d_out, int out_size, void* d_ws, size_t ws_size,
                              hipStream_t stream) {
  if (ws_size < WS_NEED) return;

  const float* x    = (const float*)d_in[0];
  const void*  msk  = d_in[1];
  const float* Wq   = (const float*)d_in[2];
  const float* Wk   = (const float*)d_in[3];
  const float* Wv   = (const float*)d_in[4];
  const float* Wp   = (const float*)d_in[5];
  const float* W1   = (const float*)d_in[6];
  const float* b1   = (const float*)d_in[7];
  const float* W2   = (const float*)d_in[8];
  const float* b2   = (const float*)d_in[9];
  const float* ln1g = (const float*)d_in[10];
  const float* ln1b = (const float*)d_in[11];
  const float* ln2g = (const float*)d_in[12];
  const float* ln2b = (const float*)d_in[13];

  char* ws = (char*)d_ws;
  short* xb    = (short*)(ws + OFF_XB);
  short* wqkv  = (short*)(ws + OFF_WQKV);
  short* Wpb   = (short*)(ws + OFF_WP);
  short* W1b   = (short*)(ws + OFF_W1);
  short* W2b   = (short*)(ws + OFF_W2);
  short* QTb   = (short*)(ws + OFF_QT);
  short* Kbh   = (short*)(ws + OFF_K);
  short* VTb   = (short*)(ws + OFF_VT);
  short* ctxb  = (short*)(ws + OFF_CTX);
  float* y1    = (float*)(ws + OFF_Y1);
  short* hb    = (short*)(ws + OFF_HB);
  short* ff1b  = (short*)(ws + OFF_FF1);
  float* y2    = (float*)(ws + OFF_Y2);
  float* mbias = (float*)(ws + OFF_MB);
  unsigned* flag = (unsigned*)(ws + OFF_FLAG);

  // mask: detect dtype, build additive bias
  hipMemsetAsync(flag, 0, 4, stream);
  mask_detect<<<8, 256, 0, stream>>>((const unsigned*)msk, flag);
  mask_convert<<<32, 256, 0, stream>>>(msk, flag, mbias);

  // all f32->bf16 conversions in one launch
  cvt_all<<<7168, 256, 0, stream>>>(x, Wq, Wk, Wv, Wp, W1, W2,
                                    xb, wqkv, Wpb, W1b, W2b);

  // fused QKV projection: N=1536 (Q^T scaled 0.125; V^T; K row-major)
  gemm_bt<0><<<dim3(64, 12), 256, 0, stream>>>(xb, wqkv, 8192, 1536, 512,
                                               nullptr, QTb, Kbh, VTb);

  // attention (MFMA flash v4: 4 strips, 128q per 2-wave block)
  flash_attn_mfma<<<dim3(S_ / 128, H_, B_), 128, 0, stream>>>(QTb, Kbh, VTb, mbias, ctxb);

  // output projection + residual (f32)
  gemm_bt2<1><<<dim3(64, 8), 128, 0, stream>>>(ctxb, Wpb, 8192, 512, 512,
                                               x, nullptr, y1);

  // LN1 -> h (bf16 only)
  ln_kernel<<<2048, 256, 0, stream>>>(y1, ln1g, ln1b, nullptr, hb);

  // FF1: gelu(h @ W1^T + b1) -> bf16
  gemm_bt<2><<<dim3(64, 16), 256, 0, stream>>>(hb, W1b, 8192, 2048, 512,
                                               b1, ff1b, nullptr, nullptr);

  // FF2: ff1 @ W2^T + b2 + h(bf16 residual)
  gemm_bt2<3><<<dim3(64, 8), 128, 0, stream>>>(ff1b, W2b, 8192, 512, 2048,
                                               b2, hb, y2);

  // LN2 -> out (f32)
  ln_kernel<<<2048, 256, 0, stream>>>(y2, ln2g, ln2b, (float*)d_out, nullptr);
}

// Round 7
// 340.785 us; speedup vs baseline: 1.0208x; 1.0208x over previous
//
#include <hip/hip_runtime.h>
#include <cstdint>
#include <cstddef>

#define B_ 4
#define S_ 2048
#define D_ 512
#define H_ 8
#define DK_ 64
#define DFF_ 2048

using s16x8  = __attribute__((ext_vector_type(8))) short;
using bf16x8 = __attribute__((ext_vector_type(8))) __bf16;
using f32x4  = __attribute__((ext_vector_type(4))) float;

__device__ __forceinline__ short f2bf(float f) {
  unsigned u = __builtin_bit_cast(unsigned, f);
  u += 0x7FFFu + ((u >> 16) & 1u);
  return (short)(u >> 16);
}
__device__ __forceinline__ float bf2f(short s) {
  unsigned u = ((unsigned)(unsigned short)s) << 16;
  return __builtin_bit_cast(float, u);
}

// async global->LDS, 16 B per lane. LDS dest = wave-uniform base + lane*16.
__device__ __forceinline__ void gl2lds16(const void* g, void* l) {
  __builtin_amdgcn_global_load_lds(
      (const __attribute__((address_space(1))) void*)g,
      (__attribute__((address_space(3))) void*)l, 16, 0, 0);
}

// ---------------- fused f32 -> bf16 conversion (all tensors, one launch) ----------------
__global__ __launch_bounds__(256)
void cvt_all(const float* __restrict__ x, const float* __restrict__ Wq,
             const float* __restrict__ Wk, const float* __restrict__ Wv,
             const float* __restrict__ Wp, const float* __restrict__ W1,
             const float* __restrict__ W2,
             short* __restrict__ xb, short* __restrict__ wqkv,
             short* __restrict__ wp, short* __restrict__ w1, short* __restrict__ w2) {
  int blk = blockIdx.x;
  const float* src; short* dst; int off;
  if (blk < 4096)      { src = x;  dst = xb;            off = blk; }
  else if (blk < 4352) { src = Wq; dst = wqkv;          off = blk - 4096; }
  else if (blk < 4608) { src = Wk; dst = wqkv + 262144; off = blk - 4352; }
  else if (blk < 4864) { src = Wv; dst = wqkv + 524288; off = blk - 4608; }
  else if (blk < 5120) { src = Wp; dst = wp;            off = blk - 4864; }
  else if (blk < 6144) { src = W1; dst = w1;            off = blk - 5120; }
  else                 { src = W2; dst = w2;            off = blk - 6144; }
  int i = (off * 256 + threadIdx.x) * 4;
  float4 v = *(const float4*)(src + i);
  *(short4*)(dst + i) = make_short4(f2bf(v.x), f2bf(v.y), f2bf(v.z), f2bf(v.w));
}

// ---------------- mask dtype detect + convert ----------------
__global__ __launch_bounds__(256) void mask_detect(const unsigned* __restrict__ m,
                                                   unsigned* __restrict__ flag) {
  int i = blockIdx.x * 256 + threadIdx.x;  // 0..2047
  unsigned v = m[i];
  if (v) atomicOr(flag, v);
}

__global__ __launch_bounds__(256) void mask_convert(const void* __restrict__ m,
                                                    const unsigned* __restrict__ flag,
                                                    float* __restrict__ mb) {
  int i = blockIdx.x * 256 + threadIdx.x;  // 0..8191
  unsigned f = *flag;
  int v;
  if ((f & ~1u) == 0u)            v = ((const int*)m)[i];
  else if (f == 0x3F800000u)      v = (((const float*)m)[i] != 0.0f);
  else                            v = ((const unsigned char*)m)[i];
  mb[i] = v ? 0.0f : -100.0f;
}

// ---------------- bf16 MFMA GEMM (m97-style, 256t, 128x128): C = A * B^T ----------------
// MODE 0: fused QKV (N=1536): n<512 -> Q^T*0.125 to [B,H,64,S]; n<1024 -> K to [B,H,S,64];
//         else V^T to [B,H,64,S]. Transposed outs use short4 along m.
// MODE 2: write bf16 [m*N+n] = gelu(acc + aux1[n])             (FF1 + bias + GELU)
constexpr int BM = 128, BN = 128, BK = 32;

template <int MODE>
__global__ __launch_bounds__(256)
void gemm_bt(const short* __restrict__ A, const short* __restrict__ B,
             int M, int N, int K,
             const float* __restrict__ aux1,
             void* __restrict__ out0, void* __restrict__ out1, void* __restrict__ out2) {
  __shared__ alignas(16) short As[BM][BK];  // unpadded: global_load_lds order
  __shared__ alignas(16) short Bs[BN][BK];

  const int tid  = threadIdx.x;
  const int lane = tid & 63;
  const int wave = tid >> 6;
  const int quad = lane >> 4;
  const int l16  = lane & 15;
  const int wm   = (wave >> 1) * 64;
  const int wn   = (wave & 1) * 64;
  const int bm   = blockIdx.x * BM;
  const int bn   = blockIdx.y * BN;

  const short* Ag = A + (size_t)(bm + wave * 32 + (lane >> 2)) * K + (lane & 3) * 8;
  const short* Bg = B + (size_t)(bn + wave * 32 + (lane >> 2)) * K + (lane & 3) * 8;
  short* AsW = &As[wave * 32][0];
  short* BsW = &Bs[wave * 32][0];
  const size_t row16 = (size_t)16 * K;

  f32x4 acc[4][4] = {};

  for (int k0 = 0; k0 < K; k0 += BK) {
    gl2lds16(Ag + k0,          AsW);
    gl2lds16(Ag + k0 + row16,  AsW + 16 * BK);
    gl2lds16(Bg + k0,          BsW);
    gl2lds16(Bg + k0 + row16,  BsW + 16 * BK);
    __syncthreads();

    bf16x8 a[4], b[4];
#pragma unroll
    for (int i = 0; i < 4; ++i)
      a[i] = __builtin_bit_cast(bf16x8, *(const s16x8*)&As[wm + i * 16 + l16][quad * 8]);
#pragma unroll
    for (int j = 0; j < 4; ++j)
      b[j] = __builtin_bit_cast(bf16x8, *(const s16x8*)&Bs[wn + j * 16 + l16][quad * 8]);
#pragma unroll
    for (int i = 0; i < 4; ++i)
#pragma unroll
      for (int j = 0; j < 4; ++j)
        acc[i][j] = __builtin_amdgcn_mfma_f32_16x16x32_bf16(a[i], b[j], acc[i][j], 0, 0, 0);
    __syncthreads();
  }

#pragma unroll
  for (int i = 0; i < 4; ++i) {
    const int m0 = bm + wm + i * 16 + quad * 4;
#pragma unroll
    for (int j = 0; j < 4; ++j) {
      const int n = bn + wn + j * 16 + l16;
      if constexpr (MODE == 0) {
        const int bb = m0 >> 11, ss0 = m0 & 2047;
        if (n < 512) {  // Q^T -> [B,H,64,S], scaled 1/8, short4 along m
          short4 pk = make_short4(f2bf(acc[i][j][0] * 0.125f), f2bf(acc[i][j][1] * 0.125f),
                                  f2bf(acc[i][j][2] * 0.125f), f2bf(acc[i][j][3] * 0.125f));
          *(short4*)((short*)out0 +
              ((((size_t)bb * H_ + (n >> 6)) * 64 + (n & 63)) * S_ + ss0)) = pk;
        } else if (n >= 1024) {  // V^T -> [B,H,64,S], short4 along m
          const int nn = n - 1024;
          short4 pk = make_short4(f2bf(acc[i][j][0]), f2bf(acc[i][j][1]),
                                  f2bf(acc[i][j][2]), f2bf(acc[i][j][3]));
          *(short4*)((short*)out2 +
              ((((size_t)bb * H_ + (nn >> 6)) * 64 + (nn & 63)) * S_ + ss0)) = pk;
        } else {  // K -> [B,H,S,64]
          const int nn = n - 512;
          const int hh = nn >> 6, dd = nn & 63;
          const size_t rowb = ((size_t)bb * H_ + hh) * S_ + ss0;
#pragma unroll
          for (int rr = 0; rr < 4; ++rr)
            ((short*)out1)[(rowb + rr) * 64 + dd] = f2bf(acc[i][j][rr]);
        }
      } else {  // MODE 2: gelu(acc + bias) -> bf16
#pragma unroll
        for (int rr = 0; rr < 4; ++rr) {
          float t = acc[i][j][rr] + aux1[n];
          float gl = 0.5f * t * (1.0f + erff(t * 0.70710678118f));
          ((short*)out0)[(size_t)(m0 + rr) * N + n] = f2bf(gl);
        }
      }
    }
  }
}

// ---------------- split-K 2-wave 128x64 GEMM (N=512 shapes) ----------------
// blockIdx.z = K-half. Plain f32 partial to outp + z*M*N; reduction is fused
// into the LN kernels. Grid doubles -> 8 waves/CU (vs 4), so barrier drains
// are covered by co-resident waves (the 1-wave/SIMD trap proj/FF2 were in).
__global__ __launch_bounds__(128)
void gemm_bt2_sk(const short* __restrict__ A, const short* __restrict__ B,
                 int M, int N, int K, float* __restrict__ outp) {
  __shared__ alignas(16) short As[128][32];
  __shared__ alignas(16) short Bs[64][32];

  const int tid  = threadIdx.x;
  const int lane = tid & 63;
  const int wave = tid >> 6;       // 0..1
  const int quad = lane >> 4;
  const int l16  = lane & 15;
  const int wm   = wave * 64;
  const int bm   = blockIdx.x * 128;
  const int bn   = blockIdx.y * 64;
  const int Kh   = K >> 1;
  const int koff = blockIdx.z * Kh;

  const int srow = wave * 16 + (lane >> 2);
  const int scol = (lane & 3) * 8;
  const short* Ag = A + (size_t)(bm + srow) * K + koff + scol;
  const short* Bg = B + (size_t)(bn + srow) * K + koff + scol;
  short* AsW = &As[wave * 16][0];
  short* BsW = &Bs[wave * 16][0];
  const size_t row32 = (size_t)32 * K;

  f32x4 acc[4][4] = {};

  for (int k0 = 0; k0 < Kh; k0 += 32) {
    gl2lds16(Ag + k0,              AsW);
    gl2lds16(Ag + k0 + row32,      AsW + 32 * 32);
    gl2lds16(Ag + k0 + 2 * row32,  AsW + 64 * 32);
    gl2lds16(Ag + k0 + 3 * row32,  AsW + 96 * 32);
    gl2lds16(Bg + k0,              BsW);
    gl2lds16(Bg + k0 + row32,      BsW + 32 * 32);
    __syncthreads();

    bf16x8 a[4], b[4];
#pragma unroll
    for (int i = 0; i < 4; ++i)
      a[i] = __builtin_bit_cast(bf16x8, *(const s16x8*)&As[wm + i * 16 + l16][quad * 8]);
#pragma unroll
    for (int j = 0; j < 4; ++j)
      b[j] = __builtin_bit_cast(bf16x8, *(const s16x8*)&Bs[j * 16 + l16][quad * 8]);
#pragma unroll
    for (int i = 0; i < 4; ++i)
#pragma unroll
      for (int j = 0; j < 4; ++j)
        acc[i][j] = __builtin_amdgcn_mfma_f32_16x16x32_bf16(a[i], b[j], acc[i][j], 0, 0, 0);
    __syncthreads();
  }

  float* dst = outp + (size_t)blockIdx.z * M * N;
#pragma unroll
  for (int i = 0; i < 4; ++i) {
    const int m0 = bm + wm + i * 16 + quad * 4;
#pragma unroll
    for (int j = 0; j < 4; ++j) {
      const int n = bn + j * 16 + l16;
#pragma unroll
      for (int rr = 0; rr < 4; ++rr)
        dst[(size_t)(m0 + rr) * N + n] = acc[i][j][rr];
    }
  }
}

// ---------------- MFMA flash attention v5 ----------------
// 4-wave blocks, 128 q/block, 32 q/wave (2 strips) -> 8 waves/CU: wave-level
// overlap covers barriers (v4's 64q/wave economy halved waves and was net 0).
// Register prefetch of next K/V tile; fixed-max softmax (scores bounded);
// P truncated to bf16 with li accumulating the truncated value (consistent);
// Q gathered from Q^T [B,H,64,S] once per block; mask row in LDS.
__global__ __launch_bounds__(256)
void flash_attn_mfma(const short* __restrict__ QTg, const short* __restrict__ Kb,
                     const short* __restrict__ Vtg, const float* __restrict__ maskbias,
                     short* __restrict__ ctxb) {
  __shared__ alignas(16) short Ks[64][72];
  __shared__ alignas(16) short Vt[64][72];
  __shared__ alignas(16) short Ps[4][32][72];
  __shared__ alignas(16) float mrow[S_];

  const int b = blockIdx.z, h = blockIdx.y;
  const int tid = threadIdx.x;
  const int w = tid >> 6, lane = tid & 63;
  const int quad = lane >> 4, l16 = lane & 15;
  const size_t base  = ((size_t)(b * H_ + h)) * S_ * DK_;  // K   [B,H,S,64]
  const size_t baseT = ((size_t)(b * H_ + h)) * DK_ * S_;  // Q^T/V^T [B,H,64,S]
  const int q0 = blockIdx.x * 128;

  // mask row for this batch -> LDS (fenced by first in-loop barrier)
  {
    const float4* mp = (const float4*)(maskbias + (size_t)b * S_);
    ((float4*)mrow)[tid]       = mp[tid];
    ((float4*)mrow)[tid + 256] = mp[tid + 256];
  }

  // Q fragments from Q^T: 2 strips x 2 k-halves, gathered once per block
  bf16x8 qa[2][2];
#pragma unroll
  for (int st = 0; st < 2; ++st) {
    const int q = q0 + w * 32 + st * 16 + l16;
#pragma unroll
    for (int c = 0; c < 2; ++c) {
      s16x8 t;
#pragma unroll
      for (int j = 0; j < 8; ++j)
        t[j] = QTg[baseT + (size_t)(c * 32 + quad * 8 + j) * S_ + q];
      qa[st][c] = __builtin_bit_cast(bf16x8, t);
    }
  }

  f32x4 Oc[2][4] = {};
  float li[2][4] = {};

  const int r = tid >> 2, c16 = (tid & 3) * 16;
  const short* kp = Kb  + base  + (size_t)r * 64 + c16;   // row = key
  const short* vp = Vtg + baseT + (size_t)r * S_ + c16;   // row = d, col = key

  // preload tile 0
  s16x8 kr0 = *(const s16x8*)(kp);
  s16x8 kr1 = *(const s16x8*)(kp + 8);
  s16x8 vr0 = *(const s16x8*)(vp);
  s16x8 vr1 = *(const s16x8*)(vp + 8);

  for (int t0 = 0; t0 < S_; t0 += 64) {
    __syncthreads();  // prev tile consumers done (also fences mrow/Q on iter 0)
    *(s16x8*)&Ks[r][c16]     = kr0;
    *(s16x8*)&Ks[r][c16 + 8] = kr1;
    *(s16x8*)&Vt[r][c16]     = vr0;
    *(s16x8*)&Vt[r][c16 + 8] = vr1;
    __syncthreads();

    if (t0 + 64 < S_) {  // prefetch next tile during compute
      kr0 = *(const s16x8*)(kp + (size_t)(t0 + 64) * 64);
      kr1 = *(const s16x8*)(kp + (size_t)(t0 + 64) * 64 + 8);
      vr0 = *(const s16x8*)(vp + t0 + 64);
      vr1 = *(const s16x8*)(vp + t0 + 64 + 8);
    }

    // S = Q K^T
    f32x4 sc[2][4] = {};
#pragma unroll
    for (int c = 0; c < 2; ++c) {
#pragma unroll
      for (int jt = 0; jt < 4; ++jt) {
        bf16x8 kb = __builtin_bit_cast(bf16x8,
            *(const s16x8*)&Ks[jt * 16 + l16][c * 32 + quad * 8]);
        sc[0][jt] = __builtin_amdgcn_mfma_f32_16x16x32_bf16(qa[0][c], kb, sc[0][jt], 0, 0, 0);
        sc[1][jt] = __builtin_amdgcn_mfma_f32_16x16x32_bf16(qa[1][c], kb, sc[1][jt], 0, 0, 0);
      }
    }

    float mb4[4];
#pragma unroll
    for (int jt = 0; jt < 4; ++jt) mb4[jt] = mrow[t0 + jt * 16 + l16];
#pragma unroll
    for (int st = 0; st < 2; ++st) {
#pragma unroll
      for (int jt = 0; jt < 4; ++jt) {
#pragma unroll
        for (int rr = 0; rr < 4; ++rr) {
          float p = __expf(sc[st][jt][rr] + mb4[jt]);
          unsigned u = __builtin_bit_cast(unsigned, p) & 0xFFFF0000u;
          li[st][rr] += __builtin_bit_cast(float, u);
          Ps[w][st * 16 + quad * 4 + rr][jt * 16 + l16] = (short)(u >> 16);
        }
      }
    }

    // O += P V
#pragma unroll
    for (int c = 0; c < 2; ++c) {
      bf16x8 pa0 = __builtin_bit_cast(bf16x8,
          *(const s16x8*)&Ps[w][l16][c * 32 + quad * 8]);
      bf16x8 pa1 = __builtin_bit_cast(bf16x8,
          *(const s16x8*)&Ps[w][16 + l16][c * 32 + quad * 8]);
#pragma unroll
      for (int dt = 0; dt < 4; ++dt) {
        bf16x8 vb = __builtin_bit_cast(bf16x8,
            *(const s16x8*)&Vt[dt * 16 + l16][c * 32 + quad * 8]);
        Oc[0][dt] = __builtin_amdgcn_mfma_f32_16x16x32_bf16(pa0, vb, Oc[0][dt], 0, 0, 0);
        Oc[1][dt] = __builtin_amdgcn_mfma_f32_16x16x32_bf16(pa1, vb, Oc[1][dt], 0, 0, 0);
      }
    }
  }

#pragma unroll
  for (int st = 0; st < 2; ++st) {
#pragma unroll
    for (int rr = 0; rr < 4; ++rr) {
      float l = li[st][rr];
#pragma unroll
      for (int m = 1; m < 16; m <<= 1) l += __shfl_xor(l, m);
      float inv = 1.f / l;
      const size_t row = (size_t)b * S_ + q0 + w * 32 + st * 16 + quad * 4 + rr;
#pragma unroll
      for (int dt = 0; dt < 4; ++dt)
        ctxb[row * (H_ * DK_) + h * 64 + dt * 16 + l16] = f2bf(Oc[st][dt][rr] * inv);
    }
  }
}

// ---------------- fused split-K reduce + LayerNorm (one wave per token) ----------------
// val = p0 + p1 (+ xres f32) (+ bf2f(hres)) (+ bias[col]); then LN; out f32/bf16.
__global__ __launch_bounds__(256)
void ln_fused(const float* __restrict__ p0, const float* __restrict__ p1,
              const float* __restrict__ xres, const short* __restrict__ hres,
              const float* __restrict__ bias,
              const float* __restrict__ g, const float* __restrict__ bb,
              float* __restrict__ out32, short* __restrict__ outb) {
  const int wave = threadIdx.x >> 6, lane = threadIdx.x & 63;
  const int token = blockIdx.x * 4 + wave;
  const size_t off = (size_t)token * D_;
  const int c = lane * 8;

  float v[8];
  {
    float4 a0 = *(const float4*)(p0 + off + c);
    float4 a1 = *(const float4*)(p0 + off + c + 4);
    float4 b0 = *(const float4*)(p1 + off + c);
    float4 b1 = *(const float4*)(p1 + off + c + 4);
    v[0]=a0.x+b0.x; v[1]=a0.y+b0.y; v[2]=a0.z+b0.z; v[3]=a0.w+b0.w;
    v[4]=a1.x+b1.x; v[5]=a1.y+b1.y; v[6]=a1.z+b1.z; v[7]=a1.w+b1.w;
  }
  if (xres) {
    float4 x0 = *(const float4*)(xres + off + c);
    float4 x1 = *(const float4*)(xres + off + c + 4);
    v[0]+=x0.x; v[1]+=x0.y; v[2]+=x0.z; v[3]+=x0.w;
    v[4]+=x1.x; v[5]+=x1.y; v[6]+=x1.z; v[7]+=x1.w;
  }
  if (hres) {
    short4 h0 = *(const short4*)(hres + off + c);
    short4 h1 = *(const short4*)(hres + off + c + 4);
    v[0]+=bf2f(h0.x); v[1]+=bf2f(h0.y); v[2]+=bf2f(h0.z); v[3]+=bf2f(h0.w);
    v[4]+=bf2f(h1.x); v[5]+=bf2f(h1.y); v[6]+=bf2f(h1.z); v[7]+=bf2f(h1.w);
  }
  if (bias) {
    float4 c0 = *(const float4*)(bias + c);
    float4 c1 = *(const float4*)(bias + c + 4);
    v[0]+=c0.x; v[1]+=c0.y; v[2]+=c0.z; v[3]+=c0.w;
    v[4]+=c1.x; v[5]+=c1.y; v[6]+=c1.z; v[7]+=c1.w;
  }

  float sum = 0.f;
#pragma unroll
  for (int i = 0; i < 8; ++i) sum += v[i];
#pragma unroll
  for (int m = 1; m < 64; m <<= 1) sum += __shfl_xor(sum, m);
  float mu = sum * (1.0f / D_);
  float vs = 0.f;
#pragma unroll
  for (int i = 0; i < 8; ++i) { v[i] -= mu; vs += v[i] * v[i]; }
#pragma unroll
  for (int m = 1; m < 64; m <<= 1) vs += __shfl_xor(vs, m);
  float rstd = rsqrtf(vs * (1.0f / D_) + 1e-5f);
#pragma unroll
  for (int i = 0; i < 8; ++i) {
    float val = v[i] * rstd * g[c + i] + bb[c + i];
    if (out32) out32[off + c + i] = val;
    if (outb)  outb[off + c + i] = f2bf(val);
  }
}

// ---------------- workspace layout (bytes) ----------------
constexpr size_t OFF_XB   = 0;                       // [8192,512] bf16
constexpr size_t OFF_WQKV = 8388608;                 // [1536,512] bf16 (Wq|Wk|Wv)
constexpr size_t OFF_WP   = 9961472;                 // [512,512] bf16
constexpr size_t OFF_W1   = 10485760;                // [2048,512] bf16
constexpr size_t OFF_W2   = 12582912;                // [512,2048] bf16
constexpr size_t OFF_QT   = 14680064;                // [B,H,64,S] bf16 (transposed!)
constexpr size_t OFF_K    = 23068672;                // [B,H,S,64] bf16
constexpr size_t OFF_VT   = 31457280;                // [B,H,64,S] bf16 (transposed!)
constexpr size_t OFF_CTX  = 39845888;                // [8192,512] bf16
constexpr size_t OFF_P0   = 48234496;                // [8192,512] f32 split-K partial 0
constexpr size_t OFF_P1   = 65011712;                // [8192,512] f32 split-K partial 1
constexpr size_t OFF_HB   = 81788928;                // [8192,512] bf16 (LN1 out)
constexpr size_t OFF_FF1  = 14680064;                // [8192,2048] bf16 (reuses QT/K/VT/CTX)
constexpr size_t OFF_MB   = 90177536;                // [8192] f32 mask bias
constexpr size_t OFF_FLAG = 90210304;                // 4 bytes
constexpr size_t WS_NEED  = 90210308;

extern "C" void kernel_launch(void* const* d_in, const int* in_sizes, int n_in,
                              void* d_out, int out_size, void* d_ws, size_t ws_size,
                              hipStream_t stream) {
  if (ws_size < WS_NEED) return;

  const float* x    = (const float*)d_in[0];
  const void*  msk  = d_in[1];
  const float* Wq   = (const float*)d_in[2];
  const float* Wk   = (const float*)d_in[3];
  const float* Wv   = (const float*)d_in[4];
  const float* Wp   = (const float*)d_in[5];
  const float* W1   = (const float*)d_in[6];
  const float* b1   = (const float*)d_in[7];
  const float* W2   = (const float*)d_in[8];
  const float* b2   = (const float*)d_in[9];
  const float* ln1g = (const float*)d_in[10];
  const float* ln1b = (const float*)d_in[11];
  const float* ln2g = (const float*)d_in[12];
  const float* ln2b = (const float*)d_in[13];

  char* ws = (char*)d_ws;
  short* xb    = (short*)(ws + OFF_XB);
  short* wqkv  = (short*)(ws + OFF_WQKV);
  short* Wpb   = (short*)(ws + OFF_WP);
  short* W1b   = (short*)(ws + OFF_W1);
  short* W2b   = (short*)(ws + OFF_W2);
  short* QTb   = (short*)(ws + OFF_QT);
  short* Kbh   = (short*)(ws + OFF_K);
  short* VTb   = (short*)(ws + OFF_VT);
  short* ctxb  = (short*)(ws + OFF_CTX);
  float* p0    = (float*)(ws + OFF_P0);   // proj/FF2 split-K partials (P0|P1 contiguous)
  short* hb    = (short*)(ws + OFF_HB);
  short* ff1b  = (short*)(ws + OFF_FF1);
  float* mbias = (float*)(ws + OFF_MB);
  unsigned* flag = (unsigned*)(ws + OFF_FLAG);

  // mask: detect dtype, build additive bias
  hipMemsetAsync(flag, 0, 4, stream);
  mask_detect<<<8, 256, 0, stream>>>((const unsigned*)msk, flag);
  mask_convert<<<32, 256, 0, stream>>>(msk, flag, mbias);

  // all f32->bf16 conversions in one launch
  cvt_all<<<7168, 256, 0, stream>>>(x, Wq, Wk, Wv, Wp, W1, W2,
                                    xb, wqkv, Wpb, W1b, W2b);

  // fused QKV projection: N=1536 (Q^T scaled 0.125; V^T; K row-major)
  gemm_bt<0><<<dim3(64, 12), 256, 0, stream>>>(xb, wqkv, 8192, 1536, 512,
                                               nullptr, QTb, Kbh, VTb);

  // attention (MFMA flash v5: 4 waves x 2 strips, 8 waves/CU)
  flash_attn_mfma<<<dim3(S_ / 128, H_, B_), 256, 0, stream>>>(QTb, Kbh, VTb, mbias, ctxb);

  // output projection, split-K=2 -> partials; reduce + residual fused into LN1
  gemm_bt2_sk<<<dim3(64, 8, 2), 128, 0, stream>>>(ctxb, Wpb, 8192, 512, 512, p0);

  // LN1: LN(p0 + p1 + x) -> h (bf16)
  ln_fused<<<2048, 256, 0, stream>>>(p0, p0 + (size_t)8192 * 512, x, nullptr, nullptr,
                                     ln1g, ln1b, nullptr, hb);

  // FF1: gelu(h @ W1^T + b1) -> bf16
  gemm_bt<2><<<dim3(64, 16), 256, 0, stream>>>(hb, W1b, 8192, 2048, 512,
                                               b1, ff1b, nullptr, nullptr);

  // FF2: split-K=2 -> partials; reduce + bias + residual fused into LN2
  gemm_bt2_sk<<<dim3(64, 8, 2), 128, 0, stream>>>(ff1b, W2b, 8192, 512, 2048, p0);

  // LN2: LN(p0 + p1 + b2 + h) -> out (f32)
  ln_fused<<<2048, 256, 0, stream>>>(p0, p0 + (size_t)8192 * 512, nullptr, hb, b2,
                                     ln2g, ln2b, (float*)d_out, nullptr);
}

// Round 8
// 324.980 us; speedup vs baseline: 1.0704x; 1.0486x over previous
//
#include <hip/hip_runtime.h>
#include <cstdint>
#include <cstddef>

#define B_ 4
#define S_ 2048
#define D_ 512
#define H_ 8
#define DK_ 64
#define DFF_ 2048

using s16x8  = __attribute__((ext_vector_type(8))) short;
using bf16x8 = __attribute__((ext_vector_type(8))) __bf16;
using f32x4  = __attribute__((ext_vector_type(4))) float;

__device__ __forceinline__ short f2bf(float f) {
  unsigned u = __builtin_bit_cast(unsigned, f);
  u += 0x7FFFu + ((u >> 16) & 1u);
  return (short)(u >> 16);
}
__device__ __forceinline__ float bf2f(short s) {
  unsigned u = ((unsigned)(unsigned short)s) << 16;
  return __builtin_bit_cast(float, u);
}

// async global->LDS, 16 B per lane. LDS dest = wave-uniform base + lane*16.
__device__ __forceinline__ void gl2lds16(const void* g, void* l) {
  __builtin_amdgcn_global_load_lds(
      (const __attribute__((address_space(1))) void*)g,
      (__attribute__((address_space(3))) void*)l, 16, 0, 0);
}

// ---------------- fused f32 -> bf16 conversion (all tensors, one launch) ----------------
__global__ __launch_bounds__(256)
void cvt_all(const float* __restrict__ x, const float* __restrict__ Wq,
             const float* __restrict__ Wk, const float* __restrict__ Wv,
             const float* __restrict__ Wp, const float* __restrict__ W1,
             const float* __restrict__ W2,
             short* __restrict__ xb, short* __restrict__ wqkv,
             short* __restrict__ wp, short* __restrict__ w1, short* __restrict__ w2) {
  int blk = blockIdx.x;
  const float* src; short* dst; int off;
  if (blk < 4096)      { src = x;  dst = xb;            off = blk; }
  else if (blk < 4352) { src = Wq; dst = wqkv;          off = blk - 4096; }
  else if (blk < 4608) { src = Wk; dst = wqkv + 262144; off = blk - 4352; }
  else if (blk < 4864) { src = Wv; dst = wqkv + 524288; off = blk - 4608; }
  else if (blk < 5120) { src = Wp; dst = wp;            off = blk - 4864; }
  else if (blk < 6144) { src = W1; dst = w1;            off = blk - 5120; }
  else                 { src = W2; dst = w2;            off = blk - 6144; }
  int i = (off * 256 + threadIdx.x) * 4;
  float4 v = *(const float4*)(src + i);
  *(short4*)(dst + i) = make_short4(f2bf(v.x), f2bf(v.y), f2bf(v.z), f2bf(v.w));
}

// ---------------- mask: single-kernel detect + convert ----------------
// Each block re-derives the dtype flag (OR of first 2048 words, block-local
// reduce) then converts its slice. int32 OR=1; f32 OR=0x3F800000; bytes mixed.
__global__ __launch_bounds__(256)
void mask_all(const void* __restrict__ m, float* __restrict__ mb) {
  __shared__ unsigned red[4];
  const unsigned* mw = (const unsigned*)m;
  const int t = threadIdx.x;
  unsigned v = 0;
#pragma unroll
  for (int i = 0; i < 8; ++i) v |= mw[t + i * 256];
#pragma unroll
  for (int s = 1; s < 64; s <<= 1) v |= __shfl_xor(v, s);
  if ((t & 63) == 0) red[t >> 6] = v;
  __syncthreads();
  unsigned f = red[0] | red[1] | red[2] | red[3];
  int i = blockIdx.x * 256 + t;
  int val;
  if ((f & ~1u) == 0u)            val = ((const int*)m)[i];
  else if (f == 0x3F800000u)      val = (((const float*)m)[i] != 0.0f);
  else                            val = ((const unsigned char*)m)[i];
  mb[i] = val ? 0.0f : -100.0f;
}

// ---------------- unified bf16 MFMA GEMM: 256t, 128x128 tile, BK=64 ----------------
// XOR-swizzled LDS (physical 16B-block = logical ^ (row&7)) -- expressed via the
// per-lane GLOBAL gather address, so global_load_lds' lane-ordered LDS writes
// stay contiguous while 128B rows avoid 16-way bank conflicts (reads land 2/bank).
// BK=64 halves barrier pairs vs BK=32 (the per-iter vmcnt drain is the cost).
// blockIdx.z = split-K slice (gridDim.z slices; partial sums for MODE 1).
// MODE 0: fused QKV (N=1536): n<512 -> Q^T*0.125 [B,H,64,S]; n<1024 -> K [B,H,S,64];
//         else V^T [B,H,64,S]. Transposed outs short4 along m.
// MODE 1: f32 partial [z*M*N + m*N + n] = acc      (proj / FF2; reduce in ln_fused)
// MODE 2: bf16 [m*N+n] = gelu(acc + aux1[n])       (FF1 + bias + GELU)
template <int MODE>
__global__ __launch_bounds__(256)
void gemm_bt(const short* __restrict__ A, const short* __restrict__ B,
             int M, int N, int K,
             const float* __restrict__ aux1,
             void* __restrict__ out0, void* __restrict__ out1, void* __restrict__ out2) {
  __shared__ alignas(16) short As[128][64];
  __shared__ alignas(16) short Bs[128][64];

  const int tid  = threadIdx.x;
  const int lane = tid & 63;
  const int wave = tid >> 6;
  const int quad = lane >> 4;
  const int l16  = lane & 15;
  const int wm   = (wave >> 1) * 64;
  const int wn   = (wave & 1) * 64;
  const int bm   = blockIdx.x * 128;
  const int bn   = blockIdx.y * 128;
  const int Kh   = K / gridDim.z;
  const int koff = blockIdx.z * Kh;

  const int srow8 = lane >> 3;   // row within an 8-row staging chunk
  const int pb    = lane & 7;    // physical 16B block within 128B row

  f32x4 acc[4][4] = {};

  for (int k0 = 0; k0 < Kh; k0 += 64) {
#pragma unroll
    for (int i = 0; i < 4; ++i) {
      const int rr = wave * 32 + i * 8 + srow8;      // tile row 0..127
      const int cb = pb ^ (rr & 7);                  // logical 16B block (swizzle)
      gl2lds16(A + (size_t)(bm + rr) * K + koff + k0 + cb * 8, &As[wave * 32 + i * 8][0]);
      gl2lds16(B + (size_t)(bn + rr) * K + koff + k0 + cb * 8, &Bs[wave * 32 + i * 8][0]);
    }
    __syncthreads();

#pragma unroll
    for (int c = 0; c < 2; ++c) {
      bf16x8 a[4], b[4];
#pragma unroll
      for (int i = 0; i < 4; ++i) {
        const int row = wm + i * 16 + l16;
        const int pba = (c * 4 + quad) ^ (row & 7);
        a[i] = __builtin_bit_cast(bf16x8, *(const s16x8*)&As[row][pba * 8]);
      }
#pragma unroll
      for (int j = 0; j < 4; ++j) {
        const int row = wn + j * 16 + l16;
        const int pbb = (c * 4 + quad) ^ (row & 7);
        b[j] = __builtin_bit_cast(bf16x8, *(const s16x8*)&Bs[row][pbb * 8]);
      }
#pragma unroll
      for (int i = 0; i < 4; ++i)
#pragma unroll
        for (int j = 0; j < 4; ++j)
          acc[i][j] = __builtin_amdgcn_mfma_f32_16x16x32_bf16(a[i], b[j], acc[i][j], 0, 0, 0);
    }
    __syncthreads();
  }

#pragma unroll
  for (int i = 0; i < 4; ++i) {
    const int m0 = bm + wm + i * 16 + quad * 4;
#pragma unroll
    for (int j = 0; j < 4; ++j) {
      const int n = bn + wn + j * 16 + l16;
      if constexpr (MODE == 0) {
        const int bb = m0 >> 11, ss0 = m0 & 2047;
        if (n < 512) {  // Q^T -> [B,H,64,S], scaled 1/8
          short4 pk = make_short4(f2bf(acc[i][j][0] * 0.125f), f2bf(acc[i][j][1] * 0.125f),
                                  f2bf(acc[i][j][2] * 0.125f), f2bf(acc[i][j][3] * 0.125f));
          *(short4*)((short*)out0 +
              ((((size_t)bb * H_ + (n >> 6)) * 64 + (n & 63)) * S_ + ss0)) = pk;
        } else if (n >= 1024) {  // V^T -> [B,H,64,S]
          const int nn = n - 1024;
          short4 pk = make_short4(f2bf(acc[i][j][0]), f2bf(acc[i][j][1]),
                                  f2bf(acc[i][j][2]), f2bf(acc[i][j][3]));
          *(short4*)((short*)out2 +
              ((((size_t)bb * H_ + (nn >> 6)) * 64 + (nn & 63)) * S_ + ss0)) = pk;
        } else {  // K -> [B,H,S,64]
          const int nn = n - 512;
          const size_t rowb = ((size_t)bb * H_ + (nn >> 6)) * S_ + ss0;
#pragma unroll
          for (int rr = 0; rr < 4; ++rr)
            ((short*)out1)[(rowb + rr) * 64 + (nn & 63)] = f2bf(acc[i][j][rr]);
        }
      } else if constexpr (MODE == 1) {  // f32 split-K partial
        float* dst = (float*)out0 + (size_t)blockIdx.z * M * N;
#pragma unroll
        for (int rr = 0; rr < 4; ++rr)
          dst[(size_t)(m0 + rr) * N + n] = acc[i][j][rr];
      } else {  // MODE 2: gelu(acc + bias) -> bf16
#pragma unroll
        for (int rr = 0; rr < 4; ++rr) {
          float t = acc[i][j][rr] + aux1[n];
          float gl = 0.5f * t * (1.0f + erff(t * 0.70710678118f));
          ((short*)out0)[(size_t)(m0 + rr) * N + n] = f2bf(gl);
        }
      }
    }
  }
}

// ---------------- MFMA flash attention v5 (R7, unchanged: decomposition plateau) ----------------
__global__ __launch_bounds__(256)
void flash_attn_mfma(const short* __restrict__ QTg, const short* __restrict__ Kb,
                     const short* __restrict__ Vtg, const float* __restrict__ maskbias,
                     short* __restrict__ ctxb) {
  __shared__ alignas(16) short Ks[64][72];
  __shared__ alignas(16) short Vt[64][72];
  __shared__ alignas(16) short Ps[4][32][72];
  __shared__ alignas(16) float mrow[S_];

  const int b = blockIdx.z, h = blockIdx.y;
  const int tid = threadIdx.x;
  const int w = tid >> 6, lane = tid & 63;
  const int quad = lane >> 4, l16 = lane & 15;
  const size_t base  = ((size_t)(b * H_ + h)) * S_ * DK_;  // K   [B,H,S,64]
  const size_t baseT = ((size_t)(b * H_ + h)) * DK_ * S_;  // Q^T/V^T [B,H,64,S]
  const int q0 = blockIdx.x * 128;

  {
    const float4* mp = (const float4*)(maskbias + (size_t)b * S_);
    ((float4*)mrow)[tid]       = mp[tid];
    ((float4*)mrow)[tid + 256] = mp[tid + 256];
  }

  bf16x8 qa[2][2];
#pragma unroll
  for (int st = 0; st < 2; ++st) {
    const int q = q0 + w * 32 + st * 16 + l16;
#pragma unroll
    for (int c = 0; c < 2; ++c) {
      s16x8 t;
#pragma unroll
      for (int j = 0; j < 8; ++j)
        t[j] = QTg[baseT + (size_t)(c * 32 + quad * 8 + j) * S_ + q];
      qa[st][c] = __builtin_bit_cast(bf16x8, t);
    }
  }

  f32x4 Oc[2][4] = {};
  float li[2][4] = {};

  const int r = tid >> 2, c16 = (tid & 3) * 16;
  const short* kp = Kb  + base  + (size_t)r * 64 + c16;
  const short* vp = Vtg + baseT + (size_t)r * S_ + c16;

  s16x8 kr0 = *(const s16x8*)(kp);
  s16x8 kr1 = *(const s16x8*)(kp + 8);
  s16x8 vr0 = *(const s16x8*)(vp);
  s16x8 vr1 = *(const s16x8*)(vp + 8);

  for (int t0 = 0; t0 < S_; t0 += 64) {
    __syncthreads();
    *(s16x8*)&Ks[r][c16]     = kr0;
    *(s16x8*)&Ks[r][c16 + 8] = kr1;
    *(s16x8*)&Vt[r][c16]     = vr0;
    *(s16x8*)&Vt[r][c16 + 8] = vr1;
    __syncthreads();

    if (t0 + 64 < S_) {
      kr0 = *(const s16x8*)(kp + (size_t)(t0 + 64) * 64);
      kr1 = *(const s16x8*)(kp + (size_t)(t0 + 64) * 64 + 8);
      vr0 = *(const s16x8*)(vp + t0 + 64);
      vr1 = *(const s16x8*)(vp + t0 + 64 + 8);
    }

    f32x4 sc[2][4] = {};
#pragma unroll
    for (int c = 0; c < 2; ++c) {
#pragma unroll
      for (int jt = 0; jt < 4; ++jt) {
        bf16x8 kb = __builtin_bit_cast(bf16x8,
            *(const s16x8*)&Ks[jt * 16 + l16][c * 32 + quad * 8]);
        sc[0][jt] = __builtin_amdgcn_mfma_f32_16x16x32_bf16(qa[0][c], kb, sc[0][jt], 0, 0, 0);
        sc[1][jt] = __builtin_amdgcn_mfma_f32_16x16x32_bf16(qa[1][c], kb, sc[1][jt], 0, 0, 0);
      }
    }

    float mb4[4];
#pragma unroll
    for (int jt = 0; jt < 4; ++jt) mb4[jt] = mrow[t0 + jt * 16 + l16];
#pragma unroll
    for (int st = 0; st < 2; ++st) {
#pragma unroll
      for (int jt = 0; jt < 4; ++jt) {
#pragma unroll
        for (int rr = 0; rr < 4; ++rr) {
          float p = __expf(sc[st][jt][rr] + mb4[jt]);
          unsigned u = __builtin_bit_cast(unsigned, p) & 0xFFFF0000u;
          li[st][rr] += __builtin_bit_cast(float, u);
          Ps[w][st * 16 + quad * 4 + rr][jt * 16 + l16] = (short)(u >> 16);
        }
      }
    }

#pragma unroll
    for (int c = 0; c < 2; ++c) {
      bf16x8 pa0 = __builtin_bit_cast(bf16x8,
          *(const s16x8*)&Ps[w][l16][c * 32 + quad * 8]);
      bf16x8 pa1 = __builtin_bit_cast(bf16x8,
          *(const s16x8*)&Ps[w][16 + l16][c * 32 + quad * 8]);
#pragma unroll
      for (int dt = 0; dt < 4; ++dt) {
        bf16x8 vb = __builtin_bit_cast(bf16x8,
            *(const s16x8*)&Vt[dt * 16 + l16][c * 32 + quad * 8]);
        Oc[0][dt] = __builtin_amdgcn_mfma_f32_16x16x32_bf16(pa0, vb, Oc[0][dt], 0, 0, 0);
        Oc[1][dt] = __builtin_amdgcn_mfma_f32_16x16x32_bf16(pa1, vb, Oc[1][dt], 0, 0, 0);
      }
    }
  }

#pragma unroll
  for (int st = 0; st < 2; ++st) {
#pragma unroll
    for (int rr = 0; rr < 4; ++rr) {
      float l = li[st][rr];
#pragma unroll
      for (int m = 1; m < 16; m <<= 1) l += __shfl_xor(l, m);
      float inv = 1.f / l;
      const size_t row = (size_t)b * S_ + q0 + w * 32 + st * 16 + quad * 4 + rr;
#pragma unroll
      for (int dt = 0; dt < 4; ++dt)
        ctxb[row * (H_ * DK_) + h * 64 + dt * 16 + l16] = f2bf(Oc[st][dt][rr] * inv);
    }
  }
}

// ---------------- fused split-K reduce + LayerNorm (one wave per token) ----------------
__global__ __launch_bounds__(256)
void ln_fused(const float* __restrict__ p0, const float* __restrict__ p1,
              const float* __restrict__ xres, const short* __restrict__ hres,
              const float* __restrict__ bias,
              const float* __restrict__ g, const float* __restrict__ bb,
              float* __restrict__ out32, short* __restrict__ outb) {
  const int wave = threadIdx.x >> 6, lane = threadIdx.x & 63;
  const int token = blockIdx.x * 4 + wave;
  const size_t off = (size_t)token * D_;
  const int c = lane * 8;

  float v[8];
  {
    float4 a0 = *(const float4*)(p0 + off + c);
    float4 a1 = *(const float4*)(p0 + off + c + 4);
    float4 b0 = *(const float4*)(p1 + off + c);
    float4 b1 = *(const float4*)(p1 + off + c + 4);
    v[0]=a0.x+b0.x; v[1]=a0.y+b0.y; v[2]=a0.z+b0.z; v[3]=a0.w+b0.w;
    v[4]=a1.x+b1.x; v[5]=a1.y+b1.y; v[6]=a1.z+b1.z; v[7]=a1.w+b1.w;
  }
  if (xres) {
    float4 x0 = *(const float4*)(xres + off + c);
    float4 x1 = *(const float4*)(xres + off + c + 4);
    v[0]+=x0.x; v[1]+=x0.y; v[2]+=x0.z; v[3]+=x0.w;
    v[4]+=x1.x; v[5]+=x1.y; v[6]+=x1.z; v[7]+=x1.w;
  }
  if (hres) {
    short4 h0 = *(const short4*)(hres + off + c);
    short4 h1 = *(const short4*)(hres + off + c + 4);
    v[0]+=bf2f(h0.x); v[1]+=bf2f(h0.y); v[2]+=bf2f(h0.z); v[3]+=bf2f(h0.w);
    v[4]+=bf2f(h1.x); v[5]+=bf2f(h1.y); v[6]+=bf2f(h1.z); v[7]+=bf2f(h1.w);
  }
  if (bias) {
    float4 c0 = *(const float4*)(bias + c);
    float4 c1 = *(const float4*)(bias + c + 4);
    v[0]+=c0.x; v[1]+=c0.y; v[2]+=c0.z; v[3]+=c0.w;
    v[4]+=c1.x; v[5]+=c1.y; v[6]+=c1.z; v[7]+=c1.w;
  }

  float sum = 0.f;
#pragma unroll
  for (int i = 0; i < 8; ++i) sum += v[i];
#pragma unroll
  for (int m = 1; m < 64; m <<= 1) sum += __shfl_xor(sum, m);
  float mu = sum * (1.0f / D_);
  float vs = 0.f;
#pragma unroll
  for (int i = 0; i < 8; ++i) { v[i] -= mu; vs += v[i] * v[i]; }
#pragma unroll
  for (int m = 1; m < 64; m <<= 1) vs += __shfl_xor(vs, m);
  float rstd = rsqrtf(vs * (1.0f / D_) + 1e-5f);
#pragma unroll
  for (int i = 0; i < 8; ++i) {
    float val = v[i] * rstd * g[c + i] + bb[c + i];
    if (out32) out32[off + c + i] = val;
    if (outb)  outb[off + c + i] = f2bf(val);
  }
}

// ---------------- workspace layout (bytes) ----------------
constexpr size_t OFF_XB   = 0;                       // [8192,512] bf16
constexpr size_t OFF_WQKV = 8388608;                 // [1536,512] bf16 (Wq|Wk|Wv)
constexpr size_t OFF_WP   = 9961472;                 // [512,512] bf16
constexpr size_t OFF_W1   = 10485760;                // [2048,512] bf16
constexpr size_t OFF_W2   = 12582912;                // [512,2048] bf16
constexpr size_t OFF_QT   = 14680064;                // [B,H,64,S] bf16 (transposed!)
constexpr size_t OFF_K    = 23068672;                // [B,H,S,64] bf16
constexpr size_t OFF_VT   = 31457280;                // [B,H,64,S] bf16 (transposed!)
constexpr size_t OFF_CTX  = 39845888;                // [8192,512] bf16
constexpr size_t OFF_P0   = 48234496;                // [8192,512] f32 split-K partial 0
constexpr size_t OFF_P1   = 65011712;                // [8192,512] f32 split-K partial 1
constexpr size_t OFF_HB   = 81788928;                // [8192,512] bf16 (LN1 out)
constexpr size_t OFF_FF1  = 14680064;                // [8192,2048] bf16 (reuses QT/K/VT/CTX)
constexpr size_t OFF_MB   = 90177536;                // [8192] f32 mask bias
constexpr size_t WS_NEED  = 90210304;

extern "C" void kernel_launch(void* const* d_in, const int* in_sizes, int n_in,
                              void* d_out, int out_size, void* d_ws, size_t ws_size,
                              hipStream_t stream) {
  if (ws_size < WS_NEED) return;

  const float* x    = (const float*)d_in[0];
  const void*  msk  = d_in[1];
  const float* Wq   = (const float*)d_in[2];
  const float* Wk   = (const float*)d_in[3];
  const float* Wv   = (const float*)d_in[4];
  const float* Wp   = (const float*)d_in[5];
  const float* W1   = (const float*)d_in[6];
  const float* b1   = (const float*)d_in[7];
  const float* W2   = (const float*)d_in[8];
  const float* b2   = (const float*)d_in[9];
  const float* ln1g = (const float*)d_in[10];
  const float* ln1b = (const float*)d_in[11];
  const float* ln2g = (const float*)d_in[12];
  const float* ln2b = (const float*)d_in[13];

  char* ws = (char*)d_ws;
  short* xb    = (short*)(ws + OFF_XB);
  short* wqkv  = (short*)(ws + OFF_WQKV);
  short* Wpb   = (short*)(ws + OFF_WP);
  short* W1b   = (short*)(ws + OFF_W1);
  short* W2b   = (short*)(ws + OFF_W2);
  short* QTb   = (short*)(ws + OFF_QT);
  short* Kbh   = (short*)(ws + OFF_K);
  short* VTb   = (short*)(ws + OFF_VT);
  short* ctxb  = (short*)(ws + OFF_CTX);
  float* p0    = (float*)(ws + OFF_P0);   // split-K partials (P0|P1 contiguous)
  short* hb    = (short*)(ws + OFF_HB);
  short* ff1b  = (short*)(ws + OFF_FF1);
  float* mbias = (float*)(ws + OFF_MB);

  // mask: fused detect + convert (one dispatch)
  mask_all<<<32, 256, 0, stream>>>(msk, mbias);

  // all f32->bf16 conversions in one launch
  cvt_all<<<7168, 256, 0, stream>>>(x, Wq, Wk, Wv, Wp, W1, W2,
                                    xb, wqkv, Wpb, W1b, W2b);

  // fused QKV projection: N=1536 (Q^T scaled 0.125; V^T; K row-major)
  gemm_bt<0><<<dim3(64, 12, 1), 256, 0, stream>>>(xb, wqkv, 8192, 1536, 512,
                                                  nullptr, QTb, Kbh, VTb);

  // attention (MFMA flash v5)
  flash_attn_mfma<<<dim3(S_ / 128, H_, B_), 256, 0, stream>>>(QTb, Kbh, VTb, mbias, ctxb);

  // output projection, split-K=2 -> f32 partials (reduce+residual in LN1)
  gemm_bt<1><<<dim3(64, 4, 2), 256, 0, stream>>>(ctxb, Wpb, 8192, 512, 512,
                                                 nullptr, p0, nullptr, nullptr);

  // LN1: LN(p0 + p1 + x) -> h (bf16)
  ln_fused<<<2048, 256, 0, stream>>>(p0, p0 + (size_t)8192 * 512, x, nullptr, nullptr,
                                     ln1g, ln1b, nullptr, hb);

  // FF1: gelu(h @ W1^T + b1) -> bf16
  gemm_bt<2><<<dim3(64, 16, 1), 256, 0, stream>>>(hb, W1b, 8192, 2048, 512,
                                                  b1, ff1b, nullptr, nullptr);

  // FF2: split-K=2 -> f32 partials (reduce+bias+residual in LN2)
  gemm_bt<1><<<dim3(64, 4, 2), 256, 0, stream>>>(ff1b, W2b, 8192, 512, 2048,
                                                 nullptr, p0, nullptr, nullptr);

  // LN2: LN(p0 + p1 + b2 + h) -> out (f32)
  ln_fused<<<2048, 256, 0, stream>>>(p0, p0 + (size_t)8192 * 512, nullptr, hb, b2,
                                     ln2g, ln2b, (float*)d_out, nullptr);
}